// Round 6
// baseline (32.496 us; speedup 1.0000x reference)
//
#include <hip/hip_runtime.h>

// Capsule agreement routing, fp32.
// preds [8,32,14,14,32,16], b [1,32,14,14,32], out v [8,32,14,14,16].
//
// 8 sites per 64-lane wave; lane (s_w = lane>>3, g = lane&7) owns rows
// i in [4g, 4g+4) x all 16 d of site s_w (64 floats resident in VGPRs).
//
// LDS: 8 KB slice per wave (4 site-slots), 32 KB per 4-wave block ->
// ~4-5 blocks/CU (2x round-4 occupancy). Staging in 2 phases of 4 sites;
// both phases' global loads issued up front (ping-pong reg buffers), one
// WAR drain between phases. All loads perfectly coalesced (1 KB/instr).
//
// XOR swizzle (bijective): site-local float4 index m of within-wave site k
// stored at slot (k&3)*128 + (m ^ k ^ ((m>>4)&4)).
//   write (fixed j): key = k ^ 4*(j&1) const -> bank-group (lane&7)^key,
//     8 lanes/group = b128 floor, conflict-free.
//   read (fixed r,u): bank-group = (4(r&1)+u) ^ s_w ^ (g&4); the g&4 term
//     spreads the 32 active lanes of a masked phase over all 8 groups ->
//     full data rate. Conflict-free.
//
// Math per pass (cross-lane = quad_perm/row_half_mirror DPP, zero LDS ops):
//   b kept in log2 domain -> e = exp2(bl) is a bare v_exp_f32
//   softmax sum: 3 local adds + 3 DPP levels; r = rcp(sum)
//   s~_d = sum_i e_i p_id : 64 lane-local FMA + 8-lane reduce (3 DPP/comp)
//   squash folded: sq = r^2|s~|^2, f = sq/(1+sq)/sqrt(sq+eps)*r
//   agreement: bl_i += (f*log2e) * dot(p_i, s~)  -- fully lane-local
// v materialized only in the epilogue (lanes g<4 write one float4 each).

#define EPSQ 1e-7f
#define LOG2E 1.442695041f

constexpr int NI = 32, ND = 16;
constexpr int SITES = 50176;          // 8*32*14*14
constexpr int OHW   = 6272;           // 32*14*14
constexpr int THREADS = 256;
constexpr int BLOCKS  = SITES / 32;   // 1568 (8 sites/wave * 4 waves/block)

__device__ __forceinline__ float dpp1(float x) {   // quad_perm xor 1
    return __int_as_float(__builtin_amdgcn_mov_dpp(__float_as_int(x), 0xB1, 0xF, 0xF, true));
}
__device__ __forceinline__ float dpp2(float x) {   // quad_perm xor 2
    return __int_as_float(__builtin_amdgcn_mov_dpp(__float_as_int(x), 0x4E, 0xF, 0xF, true));
}
__device__ __forceinline__ float dpp4(float x) {   // row_half_mirror: l -> 7-l in each 8
    return __int_as_float(__builtin_amdgcn_mov_dpp(__float_as_int(x), 0x141, 0xF, 0xF, true));
}
__device__ __forceinline__ float red8(float x) {   // sum over aligned 8-lane group
    x += dpp1(x); x += dpp2(x); x += dpp4(x); return x;
}
__device__ __forceinline__ void fma4(float4& a, float c, const float4& x) {
    a.x = fmaf(c, x.x, a.x); a.y = fmaf(c, x.y, a.y);
    a.z = fmaf(c, x.z, a.z); a.w = fmaf(c, x.w, a.w);
}
__device__ __forceinline__ float dot4(const float4& a, const float4& b) {
    return fmaf(a.x, b.x, fmaf(a.y, b.y, fmaf(a.z, b.z, a.w * b.w)));
}
__device__ __forceinline__ void red8_4(float4& a) {
    a.x += dpp1(a.x); a.y += dpp1(a.y); a.z += dpp1(a.z); a.w += dpp1(a.w);
    a.x += dpp2(a.x); a.y += dpp2(a.y); a.z += dpp2(a.z); a.w += dpp2(a.w);
    a.x += dpp4(a.x); a.y += dpp4(a.y); a.z += dpp4(a.z); a.w += dpp4(a.w);
}

__global__ __launch_bounds__(256, 4) void routing_kernel(
    const float* __restrict__ preds,
    const float* __restrict__ bparam,
    float* __restrict__ out)
{
    __shared__ float4 lds4[2048];     // 32 KB = 4 waves x 512 float4 (8 KB)
    const int tid  = threadIdx.x;
    const int lane = tid & 63;
    const int wib  = tid >> 6;
    const int wave = blockIdx.x * 4 + wib;
    const int g    = lane & 7;        // row group: rows 4g..4g+3
    const int s_w  = lane >> 3;       // within-wave site 0..7
    const int site = wave * 8 + s_w;

    float4* wlds = lds4 + wib * 512;
    const float4* pg = (const float4*)preds + (size_t)wave * 1024;  // 8 sites * 128

    // ---- routing logits: one float4 per lane = rows 4g..4g+3 of its site
    const int sohw = site % OHW;
    const float4 bv = ((const float4*)bparam)[(size_t)sohw * 8 + g];

    // ---- issue ALL global loads up front (coalesced 1 KB each), ping-pong regs
    float4 ta[8], tb[8];
    #pragma unroll
    for (int j = 0; j < 8; ++j) ta[j] = pg[j * 64 + lane];          // phase A
    #pragma unroll
    for (int j = 0; j < 8; ++j) tb[j] = pg[512 + j * 64 + lane];    // phase B

    auto write_phase = [&](int ph, const float4* t) {
        #pragma unroll
        for (int j = 0; j < 8; ++j) {
            const int x = j >> 1;                 // site slot 0..3
            const int k = ph * 4 + x;             // within-wave site
            const int m = (j & 1) * 64 + lane;    // site-local float4 index
            wlds[x * 128 + (m ^ k ^ (((j & 1) << 2)))] = t[j];
        }
    };

    float4 p[4][4];                   // [row r][comp u]: row 4g+r, d 4u..4u+3
    const int rkey = s_w ^ (g & 4);   // read XOR key (m's bit6 = g&4)
    const int rbase = (s_w & 3) * 128 + 16 * g;

    write_phase(0, ta);
    asm volatile("s_waitcnt lgkmcnt(0)" ::: "memory");
    if (s_w < 4) {
        #pragma unroll
        for (int r = 0; r < 4; ++r)
            #pragma unroll
            for (int u = 0; u < 4; ++u)
                p[r][u] = wlds[(s_w & 3) * 128 + ((16 * g + 4 * r + u) ^ rkey)];
    }
    asm volatile("s_waitcnt lgkmcnt(0)" ::: "memory");   // WAR: reads drained
    write_phase(1, tb);
    asm volatile("s_waitcnt lgkmcnt(0)" ::: "memory");
    if (s_w >= 4) {
        #pragma unroll
        for (int r = 0; r < 4; ++r)
            #pragma unroll
            for (int u = 0; u < 4; ++u)
                p[r][u] = wlds[(s_w & 3) * 128 + ((16 * g + 4 * r + u) ^ rkey)];
    }

    // logits in log2 domain
    float bl[4] = {bv.x * LOG2E, bv.y * LOG2E, bv.z * LOG2E, bv.w * LOG2E};

    float4 s0, s1, s2, s3;            // unnormalized s~, replicated across site
    float  f;                         // v = f * s~

    auto pass = [&]() {
        float e[4];
        float sm = 0.0f;
        #pragma unroll
        for (int k = 0; k < 4; ++k) { e[k] = __builtin_amdgcn_exp2f(bl[k]); sm += e[k]; }
        sm = red8(sm);
        const float r = __frcp_rn(sm);

        s0 = make_float4(0,0,0,0); s1 = make_float4(0,0,0,0);
        s2 = make_float4(0,0,0,0); s3 = make_float4(0,0,0,0);
        #pragma unroll
        for (int k = 0; k < 4; ++k) {
            fma4(s0, e[k], p[k][0]); fma4(s1, e[k], p[k][1]);
            fma4(s2, e[k], p[k][2]); fma4(s3, e[k], p[k][3]);
        }
        red8_4(s0); red8_4(s1); red8_4(s2); red8_4(s3);

        const float sqt = dot4(s0, s0) + dot4(s1, s1) + dot4(s2, s2) + dot4(s3, s3);
        const float sq  = r * r * sqt;
        f = sq * __frcp_rn(1.0f + sq) * __frsqrt_rn(sq + EPSQ) * r;
    };

    pass();

    #pragma unroll
    for (int it = 0; it < 3; ++it) {
        const float fl = f * LOG2E;
        #pragma unroll
        for (int k = 0; k < 4; ++k) {
            const float qk = dot4(p[k][0], s0) + dot4(p[k][1], s1)
                           + dot4(p[k][2], s2) + dot4(p[k][3], s3);
            bl[k] = fmaf(fl, qk, bl[k]);
        }
        pass();
    }

    // epilogue: s replicated across the site's 8 lanes; lanes g<4 write
    // float4 g -> contiguous 512 B per wave
    if (g < 4) {
        float4 w = (g == 0) ? s0 : (g == 1) ? s1 : (g == 2) ? s2 : s3;
        w.x *= f; w.y *= f; w.z *= f; w.w *= f;
        ((float4*)out)[(size_t)site * 4 + g] = w;
    }
}

extern "C" void kernel_launch(void* const* d_in, const int* in_sizes, int n_in,
                              void* d_out, int out_size, void* d_ws, size_t ws_size,
                              hipStream_t stream) {
    const float* preds  = (const float*)d_in[0];
    const float* bparam = (const float*)d_in[1];
    float* out = (float*)d_out;
    routing_kernel<<<BLOCKS, THREADS, 0, stream>>>(preds, bparam, out);
}